// Round 2
// baseline (190.024 us; speedup 1.0000x reference)
//
#include <hip/hip_runtime.h>

#define N_NODES 100000
#define N_EDGES 1600000
#define D_FEAT 64
#define NPB 128                      // nodes per bucket
#define K_BUCKETS 782                // ceil(100000/128); bucket = dst >> 7
#define CAP 2304                     // fixed bucket capacity (mean 2048 + 5.7 sigma)
#define A_BLOCKS 800
#define A_CHUNK 2000                 // 800 * 2000 == 1,600,000 exactly
#define A_THREADS 512                // 8 waves/block, ~3 blocks/CU -> ~25 waves/CU
#define S_THREADS 512                // 8 waves/block, 3 blocks/CU -> ~24 waves/CU

// ---------- Pass 1: bucketed scatter into fixed-capacity regions ----------
// cursor[b] zero-initialized; block reserves a contiguous range per bucket with
// ONE global atomic per (block,bucket); writes land in bucket's own CAP region.
__global__ __launch_bounds__(A_THREADS) void scatterA(
        const int* __restrict__ src, const int* __restrict__ dst,
        const float* __restrict__ val, int* __restrict__ cursor,
        int2* __restrict__ bdata) {
    __shared__ int sh_cnt[K_BUCKETS];
    __shared__ int sh_base[K_BUCKETS];
    for (int i = threadIdx.x; i < K_BUCKETS; i += A_THREADS) sh_cnt[i] = 0;
    __syncthreads();
    const int base = blockIdx.x * A_CHUNK;
    for (int j = threadIdx.x; j < A_CHUNK; j += A_THREADS)
        atomicAdd(&sh_cnt[dst[base + j] >> 7], 1);
    __syncthreads();
    for (int i = threadIdx.x; i < K_BUCKETS; i += A_THREADS) {
        const int c = sh_cnt[i];
        sh_base[i] = c ? (i * CAP + atomicAdd(&cursor[i], c)) : 0;
    }
    __syncthreads();
    for (int i = threadIdx.x; i < K_BUCKETS; i += A_THREADS) sh_cnt[i] = 0;
    __syncthreads();
    for (int j = threadIdx.x; j < A_CHUNK; j += A_THREADS) {
        const int e = base + j;
        const int d = dst[e];
        const int b = d >> 7;
        const int slot = atomicAdd(&sh_cnt[b], 1);
        // pack: src in bits [0,17), dst_local in bits [17,24)
        bdata[sh_base[b] + slot] =
            make_int2(src[e] | ((d & 127) << 17), __float_as_int(val[e]));
    }
}

// ---------- Pass 2 (fused): per-bucket counting sort in LDS + SpMM ----------
// One block per bucket, 512 threads (8 waves) for latency hiding. Sorted edge
// list never touches global memory; SpMM gathers x rows straight from LDS
// metadata. 16 lanes per row, float4 register acc, gather unrolled x4.
__global__ __launch_bounds__(S_THREADS) void sort_spmm(
        const float* __restrict__ x, const int2* __restrict__ bdata,
        const int* __restrict__ cursor, float* __restrict__ out) {
    __shared__ int2 sh_e[CAP];        // 18432 B raw bucket
    __shared__ int2 sh_s[CAP];        // 18432 B sorted bucket
    __shared__ int cnt[NPB];          // histogram -> inclusive scan
    __shared__ int cur[NPB];          // scatter cursors
    const int b = blockIdx.x;
    const int count = min(cursor[b], CAP);
    const int base = b * CAP;
    const int t = threadIdx.x;

    if (t < NPB) cnt[t] = 0;
    __syncthreads();
    for (int j = t; j < count; j += S_THREADS) {
        const int2 e = bdata[base + j];
        sh_e[j] = e;
        atomicAdd(&cnt[e.x >> 17], 1);
    }
    __syncthreads();
    const int v = (t < NPB) ? cnt[t] : 0;     // per-node degree
    for (int off = 1; off < NPB; off <<= 1) { // Hillis-Steele inclusive scan
        int u = 0;
        if (t < NPB && t >= off) u = cnt[t - off];
        __syncthreads();
        if (t < NPB) cnt[t] += u;
        __syncthreads();
    }
    if (t < NPB) cur[t] = cnt[t] - v;         // exclusive scan = row begin
    __syncthreads();
    for (int j = t; j < count; j += S_THREADS) {  // scatter sorted into LDS
        const int2 pv = sh_e[j];
        const int dl = pv.x >> 17;
        const int slot = atomicAdd(&cur[dl], 1);
        sh_s[slot] = make_int2(pv.x & 0x1FFFF, pv.y);
    }
    __syncthreads();

    // SpMM: 32 row-groups of 16 lanes; each group walks 4 rows of the bucket.
    const int lane = t & 15;                  // float4 chunk of the 64-feat row
    const int rg = t >> 4;
    const int row0 = b * NPB;
    for (int r = rg; r < NPB; r += S_THREADS / 16) {
        const int node = row0 + r;
        if (node >= N_NODES) continue;        // only in the last bucket
        const int beg = r ? cnt[r - 1] : 0;
        const int end = cnt[r];
        float4 acc = {0.f, 0.f, 0.f, 0.f};
        int j = beg;
        for (; j + 4 <= end; j += 4) {        // four gathers in flight
            const int2 p0 = sh_s[j];
            const int2 p1 = sh_s[j + 1];
            const int2 p2 = sh_s[j + 2];
            const int2 p3 = sh_s[j + 3];
            const float4 m0 = ((const float4*)(x + (size_t)p0.x * D_FEAT))[lane];
            const float4 m1 = ((const float4*)(x + (size_t)p1.x * D_FEAT))[lane];
            const float4 m2 = ((const float4*)(x + (size_t)p2.x * D_FEAT))[lane];
            const float4 m3 = ((const float4*)(x + (size_t)p3.x * D_FEAT))[lane];
            const float v0 = __int_as_float(p0.y);
            const float v1 = __int_as_float(p1.y);
            const float v2 = __int_as_float(p2.y);
            const float v3 = __int_as_float(p3.y);
            acc.x += v0 * m0.x + v1 * m1.x + v2 * m2.x + v3 * m3.x;
            acc.y += v0 * m0.y + v1 * m1.y + v2 * m2.y + v3 * m3.y;
            acc.z += v0 * m0.z + v1 * m1.z + v2 * m2.z + v3 * m3.z;
            acc.w += v0 * m0.w + v1 * m1.w + v2 * m2.w + v3 * m3.w;
        }
        for (; j < end; ++j) {
            const int2 p0 = sh_s[j];
            const float4 m0 = ((const float4*)(x + (size_t)p0.x * D_FEAT))[lane];
            const float v0 = __int_as_float(p0.y);
            acc.x += v0 * m0.x;
            acc.y += v0 * m0.y;
            acc.z += v0 * m0.z;
            acc.w += v0 * m0.w;
        }
        ((float4*)(out + (size_t)node * D_FEAT))[lane] = acc;  // coalesced 256B
    }
}

extern "C" void kernel_launch(void* const* d_in, const int* in_sizes, int n_in,
                              void* d_out, int out_size, void* d_ws, size_t ws_size,
                              hipStream_t stream) {
    const float* x        = (const float*)d_in[0];
    const float* edge_val = (const float*)d_in[1];
    const int*   edge_src = (const int*)d_in[2];
    const int*   edge_dst = (const int*)d_in[3];
    float* out = (float*)d_out;

    // Workspace: cursor (782 ints, 8B-aligned size) + bdata (~14.4 MB)
    int* ws     = (int*)d_ws;
    int* cursor = ws;                           // K_BUCKETS ints (3128 B, 8B-aligned)
    int2* bdata = (int2*)(ws + K_BUCKETS);      // K * CAP entries

    hipMemsetAsync(cursor, 0, K_BUCKETS * sizeof(int), stream);

    scatterA <<<A_BLOCKS, A_THREADS, 0, stream>>>(edge_src, edge_dst, edge_val,
                                                  cursor, bdata);
    sort_spmm<<<K_BUCKETS, S_THREADS, 0, stream>>>(x, bdata, cursor, out);
}

// Round 3
// 171.088 us; speedup vs baseline: 1.1107x; 1.1107x over previous
//
#include <hip/hip_runtime.h>

#define N_NODES 100000
#define N_EDGES 1600000
#define D_FEAT 64
#define NPB 128                      // nodes per bucket
#define K_BUCKETS 782                // ceil(100000/128); bucket = dst >> 7
#define CAP 2304                     // fixed bucket capacity (mean 2048 + 5.7 sigma)
#define A_BLOCKS 400
#define A_CHUNK 4000                 // 400 * 4000 == 1,600,000 exactly
#define A_THREADS 512
#define S_THREADS 256                // measured best (R1: 62.4us vs R2 512t: 65.9us)

typedef long long i64;
typedef float f4 __attribute__((ext_vector_type(4)));

// ---------- Pass 1: bucket-sorted scatter with coalesced write-out ----------
// Chunk of 4000 edges is counting-sorted BY BUCKET inside LDS, then written
// out in sorted order: consecutive lanes hit consecutive addresses within each
// bucket run (~5.1 edges = 41B), ~5x fewer write transactions than the old
// per-edge random scatter. One global atomic per (block,bucket) reserves the
// contiguous range; per-edge global index is precomputed during LDS ranking.
__global__ __launch_bounds__(A_THREADS) void scatterA(
        const int* __restrict__ src, const int* __restrict__ dst,
        const float* __restrict__ val, int* __restrict__ cursor,
        int2* __restrict__ bdata) {
    __shared__ int cnt[K_BUCKETS];     // per-bucket count in this chunk
    __shared__ int lstart[K_BUCKETS];  // exclusive scan of cnt
    __shared__ int adj[K_BUCKETS];     // global_base - lstart  (gidx = adj + rank)
    __shared__ int cur[K_BUCKETS];     // running rank cursor
    __shared__ int sums[A_THREADS];    // scan workspace
    __shared__ int2 staged[A_CHUNK];   // 32000 B bucket-sorted records
    __shared__ int gidx[A_CHUNK];      // 16000 B per-edge global target
    const int t = threadIdx.x;
    const int base = blockIdx.x * A_CHUNK;

    for (int i = t; i < K_BUCKETS; i += A_THREADS) cnt[i] = 0;
    __syncthreads();
    for (int j = t; j < A_CHUNK; j += A_THREADS)
        atomicAdd(&cnt[dst[base + j] >> 7], 1);
    __syncthreads();

    // Ordered exclusive scan of cnt[0..781] -> lstart. Thread t owns pair
    // (2t, 2t+1); 782 = 2*391 exactly. Hillis-Steele over 512 partials.
    int s0 = 0, s1 = 0;
    if (t < K_BUCKETS / 2) { s0 = cnt[2 * t]; s1 = cnt[2 * t + 1]; }
    sums[t] = s0 + s1;
    __syncthreads();
    for (int off = 1; off < A_THREADS; off <<= 1) {
        const int u = (t >= off) ? sums[t - off] : 0;
        __syncthreads();
        sums[t] += u;
        __syncthreads();
    }
    if (t < K_BUCKETS / 2) {
        const int excl = sums[t] - (s0 + s1);
        lstart[2 * t]     = excl;
        lstart[2 * t + 1] = excl + s0;
    }
    __syncthreads();

    for (int i = t; i < K_BUCKETS; i += A_THREADS) {
        const int c = cnt[i];
        const int ls = lstart[i];
        cur[i] = ls;
        adj[i] = c ? (i * CAP + atomicAdd(&cursor[i], c)) - ls : 0;
    }
    __syncthreads();

    // Rank + stage into bucket-sorted LDS order; record global target.
    for (int j = t; j < A_CHUNK; j += A_THREADS) {
        const int e = base + j;
        const int d = dst[e];
        const int b = d >> 7;
        const int s = __builtin_nontemporal_load(src + e);
        const float v = __builtin_nontemporal_load(val + e);
        const int r = atomicAdd(&cur[b], 1);
        staged[r] = make_int2(s | ((d & 127) << 17), __float_as_int(v));
        gidx[r] = adj[b] + r;
    }
    __syncthreads();

    // Coalesced write-out: consecutive j -> consecutive addresses within runs.
    for (int j = t; j < A_CHUNK; j += A_THREADS) {
        const int2 pv = staged[j];
        const i64 raw = (i64)(unsigned)pv.x | ((i64)pv.y << 32);
        __builtin_nontemporal_store(raw, (i64*)(bdata + gidx[j]));
    }
}

// ---------- Pass 2 (fused): per-bucket counting sort in LDS + SpMM ----------
// One block per bucket, 256 threads (measured optimum). Sorted edge list never
// touches global memory; SpMM gathers x rows straight from LDS metadata.
// Nontemporal on single-use streams (bdata in, out) keeps x resident in L2.
__global__ __launch_bounds__(S_THREADS) void sort_spmm(
        const float* __restrict__ x, const int2* __restrict__ bdata,
        const int* __restrict__ cursor, float* __restrict__ out) {
    __shared__ int2 sh_e[CAP];        // 18432 B raw bucket
    __shared__ int2 sh_s[CAP];        // 18432 B sorted bucket
    __shared__ int cnt[NPB];          // histogram -> inclusive scan
    __shared__ int cur[NPB];          // scatter cursors
    const int b = blockIdx.x;
    const int count = min(cursor[b], CAP);
    const int base = b * CAP;
    const int t = threadIdx.x;

    if (t < NPB) cnt[t] = 0;
    __syncthreads();
    for (int j = t; j < count; j += S_THREADS) {
        const i64 raw = __builtin_nontemporal_load((const i64*)(bdata + base + j));
        const int2 e = make_int2((int)(unsigned)raw, (int)(raw >> 32));
        sh_e[j] = e;
        atomicAdd(&cnt[e.x >> 17], 1);
    }
    __syncthreads();
    const int v = (t < NPB) ? cnt[t] : 0;     // per-node degree
    for (int off = 1; off < NPB; off <<= 1) { // Hillis-Steele inclusive scan
        int u = 0;
        if (t < NPB && t >= off) u = cnt[t - off];
        __syncthreads();
        if (t < NPB) cnt[t] += u;
        __syncthreads();
    }
    if (t < NPB) cur[t] = cnt[t] - v;         // exclusive scan = row begin
    __syncthreads();
    for (int j = t; j < count; j += S_THREADS) {  // scatter sorted into LDS
        const int2 pv = sh_e[j];
        const int dl = pv.x >> 17;
        const int slot = atomicAdd(&cur[dl], 1);
        sh_s[slot] = make_int2(pv.x & 0x1FFFF, pv.y);
    }
    __syncthreads();

    // SpMM: 16 row-groups of 16 lanes; each group walks 8 rows of the bucket.
    const int lane = t & 15;                  // float4 chunk of the 64-feat row
    const int rg = t >> 4;
    const int row0 = b * NPB;
    for (int r = rg; r < NPB; r += S_THREADS / 16) {
        const int node = row0 + r;
        if (node >= N_NODES) continue;        // only in the last bucket
        const int beg = r ? cnt[r - 1] : 0;
        const int end = cnt[r];
        float4 acc = {0.f, 0.f, 0.f, 0.f};
        int j = beg;
        for (; j + 4 <= end; j += 4) {        // four gathers in flight
            const int2 p0 = sh_s[j];
            const int2 p1 = sh_s[j + 1];
            const int2 p2 = sh_s[j + 2];
            const int2 p3 = sh_s[j + 3];
            const float4 m0 = ((const float4*)(x + (size_t)p0.x * D_FEAT))[lane];
            const float4 m1 = ((const float4*)(x + (size_t)p1.x * D_FEAT))[lane];
            const float4 m2 = ((const float4*)(x + (size_t)p2.x * D_FEAT))[lane];
            const float4 m3 = ((const float4*)(x + (size_t)p3.x * D_FEAT))[lane];
            const float v0 = __int_as_float(p0.y);
            const float v1 = __int_as_float(p1.y);
            const float v2 = __int_as_float(p2.y);
            const float v3 = __int_as_float(p3.y);
            acc.x += v0 * m0.x + v1 * m1.x + v2 * m2.x + v3 * m3.x;
            acc.y += v0 * m0.y + v1 * m1.y + v2 * m2.y + v3 * m3.y;
            acc.z += v0 * m0.z + v1 * m1.z + v2 * m2.z + v3 * m3.z;
            acc.w += v0 * m0.w + v1 * m1.w + v2 * m2.w + v3 * m3.w;
        }
        for (; j < end; ++j) {
            const int2 p0 = sh_s[j];
            const float4 m0 = ((const float4*)(x + (size_t)p0.x * D_FEAT))[lane];
            const float v0 = __int_as_float(p0.y);
            acc.x += v0 * m0.x;
            acc.y += v0 * m0.y;
            acc.z += v0 * m0.z;
            acc.w += v0 * m0.w;
        }
        const f4 accv = {acc.x, acc.y, acc.z, acc.w};
        __builtin_nontemporal_store(accv, (f4*)(out + (size_t)node * D_FEAT) + lane);
    }
}

extern "C" void kernel_launch(void* const* d_in, const int* in_sizes, int n_in,
                              void* d_out, int out_size, void* d_ws, size_t ws_size,
                              hipStream_t stream) {
    const float* x        = (const float*)d_in[0];
    const float* edge_val = (const float*)d_in[1];
    const int*   edge_src = (const int*)d_in[2];
    const int*   edge_dst = (const int*)d_in[3];
    float* out = (float*)d_out;

    // Workspace: cursor (782 ints, 8B-aligned size) + bdata (~14.4 MB)
    int* ws     = (int*)d_ws;
    int* cursor = ws;                           // K_BUCKETS ints (3128 B, 8B-aligned)
    int2* bdata = (int2*)(ws + K_BUCKETS);      // K * CAP entries

    hipMemsetAsync(cursor, 0, K_BUCKETS * sizeof(int), stream);

    scatterA <<<A_BLOCKS, A_THREADS, 0, stream>>>(edge_src, edge_dst, edge_val,
                                                  cursor, bdata);
    sort_spmm<<<K_BUCKETS, S_THREADS, 0, stream>>>(x, bdata, cursor, out);
}